// Round 1
// baseline (665.994 us; speedup 1.0000x reference)
//
#include <hip/hip_runtime.h>
#include <stdint.h>

// Problem constants
#define NPOS   65536      // 64*32*32 positions
#define CDIM   256
#define KCODES 1024
// GEMM tiling
#define MT 32             // positions per block
#define KT 256            // codes per block (blockIdx.y covers 4 chunks)
#define CT 16             // c per LDS chunk

// ---------------------------------------------------------------- e_sq[k]
__global__ void esq_kernel(const float* __restrict__ emb, float* __restrict__ e_sq) {
    int k = blockIdx.x;
    int l = threadIdx.x;                       // 64 lanes
    const float4 v = ((const float4*)(emb + (size_t)k * CDIM))[l];
    float s = v.x * v.x + v.y * v.y + v.z * v.z + v.w * v.w;
#pragma unroll
    for (int off = 32; off >= 1; off >>= 1) s += __shfl_down(s, off, 64);
    if (l == 0) e_sq[k] = s;
}

// ---------------------------------------------------------------- z_sq[pos]
__global__ void zsq_kernel(const float* __restrict__ z, float* __restrict__ z_sq) {
    int bh = blockIdx.x;                       // b*32 + h
    int b = bh >> 5, h = bh & 31;
    int tid = threadIdx.x;
    int w = tid & 31, cg = tid >> 5;           // cg 0..7
    const float* zp = z + (size_t)b * 262144 + h * 32 + w;
    float s = 0.f;
    for (int c = cg * 32; c < cg * 32 + 32; ++c) {
        float v = zp[(size_t)c * 1024];
        s = fmaf(v, v, s);
    }
    __shared__ float red[8][32];
    red[cg][w] = s;
    __syncthreads();
    if (tid < 32) {
        float t = 0.f;
#pragma unroll
        for (int g = 0; g < 8; ++g) t += red[g][tid];
        z_sq[bh * 32 + tid] = t;
    }
}

// ------------------------------------------- fused distance GEMM + argmin
// block: 256 threads, tile = MT(32) pos x KT(256) codes, full C=256.
// packed[pos] = (bits(1.0f + e_sq - 2 z.e) << 32) | k ; global atomicMin.
__global__ __launch_bounds__(256)
void gemm_argmin(const float* __restrict__ z, const float* __restrict__ emb,
                 const float* __restrict__ e_sq, unsigned long long* __restrict__ packed)
{
    __shared__ float As[CDIM][MT];    // [c][pos]  32 KB
    __shared__ float Bs[CT][KT];      // [c][code] 16 KB

    const int tid = threadIdx.x;
    const int tx = tid & 31, ty = tid >> 5;    // tx -> codes, ty -> pos group
    const int mblk = blockIdx.x;               // 0..2047
    const int b  = mblk >> 5;
    const int s0 = (mblk & 31) << 5;           // spatial offset within image
    const int k0 = blockIdx.y << 8;            // code chunk base

    // stage A once: 256 c x 32 pos, coalesced float4 (positions contiguous)
    {
        const int pos4 = tid & 7, cA = tid >> 3;          // cA 0..31
        const float* zb = z + (size_t)b * 262144 + s0 + (pos4 << 2);
#pragma unroll
        for (int p = 0; p < 8; ++p) {
            int c = cA + (p << 5);
            float4 v = *(const float4*)(zb + (size_t)c * 1024);
            *(float4*)&As[c][pos4 << 2] = v;
        }
    }

    float acc[4][8];
#pragma unroll
    for (int p = 0; p < 4; ++p)
#pragma unroll
        for (int j = 0; j < 8; ++j) acc[p][j] = 0.f;

    const int c4 = tid & 3, kk = tid >> 2;     // B staging map
    for (int cc = 0; cc < CDIM; cc += CT) {
        __syncthreads();
        // stage B chunk: CT x 256 codes (transpose to [c][code])
#pragma unroll
        for (int p = 0; p < 4; ++p) {
            int k = kk + (p << 6);
            float4 v = *(const float4*)(emb + (size_t)(k0 + k) * CDIM + cc + (c4 << 2));
            Bs[(c4 << 2) + 0][k] = v.x;
            Bs[(c4 << 2) + 1][k] = v.y;
            Bs[(c4 << 2) + 2][k] = v.z;
            Bs[(c4 << 2) + 3][k] = v.w;
        }
        __syncthreads();
#pragma unroll
        for (int c = 0; c < CT; ++c) {
            const float4 a  = *(const float4*)&As[cc + c][ty << 2];
            const float4 p0 = *(const float4*)&Bs[c][tx << 2];
            const float4 p1 = *(const float4*)&Bs[c][128 + (tx << 2)];
            const float av[4] = {a.x, a.y, a.z, a.w};
            const float bv[8] = {p0.x, p0.y, p0.z, p0.w, p1.x, p1.y, p1.z, p1.w};
#pragma unroll
            for (int p = 0; p < 4; ++p)
#pragma unroll
                for (int j = 0; j < 8; ++j)
                    acc[p][j] = fmaf(av[p], bv[j], acc[p][j]);
        }
    }

    // epilogue: val = 1 + e_sq - 2 z.e (always positive here), pack+argmin
    float ev[8];
#pragma unroll
    for (int j = 0; j < 4; ++j) {
        ev[j]     = e_sq[k0 + (tx << 2) + j];
        ev[4 + j] = e_sq[k0 + 128 + (tx << 2) + j];
    }
#pragma unroll
    for (int p = 0; p < 4; ++p) {
        float mv = 1e30f; int mk = 0;
#pragma unroll
        for (int j = 0; j < 4; ++j) {
            float v = 1.0f + ev[j] - 2.f * acc[p][j];
            if (v < mv) { mv = v; mk = (tx << 2) + j; }
        }
#pragma unroll
        for (int j = 0; j < 4; ++j) {
            float v = 1.0f + ev[4 + j] - 2.f * acc[p][4 + j];
            if (v < mv) { mv = v; mk = 128 + (tx << 2) + j; }
        }
        unsigned long long pk =
            ((unsigned long long)__float_as_uint(mv) << 32) | (unsigned)(k0 + mk);
#pragma unroll
        for (int off = 1; off < 32; off <<= 1) {
            unsigned long long o = __shfl_xor(pk, off, 64);
            if (o < pk) pk = o;
        }
        if (tx == 0) {
            int pos = (mblk << 5) + (ty << 2) + p;
            atomicMin(&packed[pos], pk);
        }
    }
}

// ---------------------------------------------------------------- z_q gather
__global__ void gather_kernel(const float* __restrict__ emb,
                              const unsigned long long* __restrict__ packed,
                              float* __restrict__ out)
{
    unsigned i = blockIdx.x * 256 + threadIdx.x;     // 16.7M elements
    int w = i & 31, h = (i >> 5) & 31, c = (i >> 10) & 255, b = i >> 18;
    int pos = (b << 10) | (h << 5) | w;
    unsigned idx = (unsigned)(packed[pos] & 0xFFFFFFFFull);
    out[i] = emb[(size_t)idx * CDIM + c];
}

// ---------------------------------------------------------------- loss
__global__ void loss_kernel(const unsigned long long* __restrict__ packed,
                            const float* __restrict__ z_sq, float* __restrict__ loss)
{
    int i = blockIdx.x * 256 + threadIdx.x;          // 65536 positions
    float d = z_sq[i] + (__uint_as_float((unsigned)(packed[i] >> 32)) - 1.0f);
#pragma unroll
    for (int off = 32; off >= 1; off >>= 1) d += __shfl_down(d, off, 64);
    __shared__ float red[4];
    int lane = threadIdx.x & 63, wv = threadIdx.x >> 6;
    if (lane == 0) red[wv] = d;
    __syncthreads();
    if (threadIdx.x == 0) {
        float s = (red[0] + red[1]) + (red[2] + red[3]);
        atomicAdd(loss, s * (1.25f / 16777216.f));   // (1+beta) * mean
    }
}

extern "C" void kernel_launch(void* const* d_in, const int* in_sizes, int n_in,
                              void* d_out, int out_size, void* d_ws, size_t ws_size,
                              hipStream_t stream)
{
    const float* z   = (const float*)d_in[0];
    const float* emb = (const float*)d_in[1];
    float* out = (float*)d_out;
    unsigned long long* packed = (unsigned long long*)d_ws;              // 512 KB
    float* z_sq = (float*)((char*)d_ws + (size_t)NPOS * 8);              // 256 KB
    float* e_sq = (float*)((char*)d_ws + (size_t)NPOS * 8 + NPOS * 4);   // 4 KB
    float* loss = out + 16777216;

    hipMemsetAsync(packed, 0xFF, (size_t)NPOS * 8, stream);  // u64 max sentinel
    hipMemsetAsync(loss, 0, sizeof(float), stream);

    esq_kernel<<<KCODES, 64, 0, stream>>>(emb, e_sq);
    zsq_kernel<<<2048, 256, 0, stream>>>(z, z_sq);
    gemm_argmin<<<dim3(2048, 4), 256, 0, stream>>>(z, emb, e_sq, packed);
    gather_kernel<<<65536, 256, 0, stream>>>(emb, packed, out);
    loss_kernel<<<256, 256, 0, stream>>>(packed, z_sq, loss);
}

// Round 2
// 348.445 us; speedup vs baseline: 1.9113x; 1.9113x over previous
//
#include <hip/hip_runtime.h>
#include <stdint.h>

typedef unsigned long long u64;
typedef __attribute__((ext_vector_type(8))) short short8;
typedef __attribute__((ext_vector_type(4))) float floatx4;

#define NPOS   65536
#define CDIM   256
#define KCODES 1024

// ---- bf16 split helpers (round-to-nearest-even) ----
__device__ __forceinline__ ushort f2bf(float x) {
    unsigned u = __float_as_uint(x);
    return (ushort)((u + 0x7FFFu + ((u >> 16) & 1u)) >> 16);
}
__device__ __forceinline__ float bf2f(ushort h) {
    return __uint_as_float(((unsigned)h) << 16);
}
__device__ __forceinline__ void gload16(const void* g, void* l) {
    __builtin_amdgcn_global_load_lds((const __attribute__((address_space(1))) void*)g,
                                     (__attribute__((address_space(3))) void*)l, 16, 0, 0);
}

// ------------------------------------------------ emb -> [k][512] bf16 hi|lo + e_sq
__global__ void emb_prep(const float* __restrict__ emb, ushort* __restrict__ emb2,
                         float* __restrict__ e_sq) {
    int k = blockIdx.x, l = threadIdx.x;            // 64 lanes
    float4 v = ((const float4*)(emb + (size_t)k * CDIM))[l];
    float s = v.x * v.x + v.y * v.y + v.z * v.z + v.w * v.w;
    ushort h[4], lo[4];
    float vv[4] = {v.x, v.y, v.z, v.w};
#pragma unroll
    for (int j = 0; j < 4; ++j) { h[j] = f2bf(vv[j]); lo[j] = f2bf(vv[j] - bf2f(h[j])); }
    *(ushort4*)(emb2 + (size_t)k * 512 + l * 4)       = make_ushort4(h[0], h[1], h[2], h[3]);
    *(ushort4*)(emb2 + (size_t)k * 512 + 256 + l * 4) = make_ushort4(lo[0], lo[1], lo[2], lo[3]);
#pragma unroll
    for (int off = 32; off >= 1; off >>= 1) s += __shfl_down(s, off, 64);
    if (l == 0) e_sq[k] = s;
}

// ------------------------------------------------ z [64][256][1024] -> zt [pos][512] bf16 hi|lo, + z_sq
__global__ __launch_bounds__(256)
void zprep(const float* __restrict__ z, ushort* __restrict__ zt, float* __restrict__ z_sq)
{
    __shared__ float tile[64][65];
    __shared__ float red[4][64];
    const int t = threadIdx.x;
    const int b = blockIdx.x >> 4, st = blockIdx.x & 15, ct = blockIdx.y;
    const int s0 = st << 6, c0 = ct << 6;
    const int s_in = t & 63, c_grp = t >> 6;
    const float* zp = z + ((size_t)b * 256 + c0 + c_grp * 16) * 1024 + s0 + s_in;
    float ps = 0.f;
#pragma unroll
    for (int i = 0; i < 16; ++i) {
        float v = zp[(size_t)i * 1024];
        tile[c_grp * 16 + i][s_in] = v;
        ps = fmaf(v, v, ps);
    }
    red[c_grp][s_in] = ps;
    __syncthreads();
    if (t < 64) {
        float s = (red[0][t] + red[1][t]) + (red[2][t] + red[3][t]);
        atomicAdd(&z_sq[b * 1024 + s0 + t], s);
    }
    const int cp = t & 31, pg = t >> 5;
#pragma unroll
    for (int j = 0; j < 8; ++j) {
        int p = (pg << 3) + j;
        float v0 = tile[2 * cp + 0][p], v1 = tile[2 * cp + 1][p];
        ushort h0 = f2bf(v0), h1 = f2bf(v1);
        ushort l0 = f2bf(v0 - bf2f(h0)), l1 = f2bf(v1 - bf2f(h1));
        size_t rowb = (size_t)(b * 1024 + s0 + p) * 512 + c0 + 2 * cp;
        *(ushort2*)(zt + rowb)       = make_ushort2(h0, h1);
        *(ushort2*)(zt + rowb + 256) = make_ushort2(l0, l1);
    }
}

// ------------------------------------------------ MFMA GEMM (K=768 bf16x3) + argmin
// A' = [z_hi | z_lo | z_hi], B' = [e_hi | e_hi | e_lo]; dist = 1 + e_sq - 2*dot
__global__ __launch_bounds__(256)
void mfma_gemm_argmin(const ushort* __restrict__ zt, const ushort* __restrict__ emb2,
                      const float* __restrict__ e_sq, u64* __restrict__ packed)
{
    __shared__ ushort As[128 * 64];   // [row][8 granules of 8 bf16], XOR-swizzled, 16 KB
    __shared__ ushort Bs[128 * 64];

    const int tid  = threadIdx.x;
    const int wave = tid >> 6, lane = tid & 63;
    const int m0 = blockIdx.x << 7;           // 512 blocks of 128 positions
    const int n0 = blockIdx.y << 7;           // 8 blocks of 128 codes
    const int wm = wave & 1, wn = wave >> 1;  // 2x2 wave grid, each wave 64x64
    const int srow = lane >> 3, scol = lane & 7;
    const int q = lane >> 4, r = lane & 15;

    floatx4 acc[4][4] = {};

    for (int kt = 0; kt < 12; ++kt) {
        const int kb = kt << 6;
        const int kA = (kb < 512) ? kb : kb - 512;   // zt: hi(0..255) lo(256..511) hi
        const int kB = (kb < 256) ? kb : kb - 256;   // emb2: hi hi lo
        __syncthreads();
#pragma unroll
        for (int i = 0; i < 4; ++i) {
            const int row = (i << 5) + (wave << 3) + srow;
            const int src16 = scol ^ (row & 7);
            gload16(zt   + (size_t)(m0 + row) * 512 + kA + src16 * 8, As + row * 64 + scol * 8);
            gload16(emb2 + (size_t)(n0 + row) * 512 + kB + src16 * 8, Bs + row * 64 + scol * 8);
        }
        __syncthreads();
#pragma unroll
        for (int ks = 0; ks < 2; ++ks) {
            short8 fa[4], fb[4];
#pragma unroll
            for (int mt = 0; mt < 4; ++mt) {
                const int row = (wm << 6) + (mt << 4) + r;
                const int g = ((ks << 2) + q) ^ (row & 7);
                fa[mt] = *(const short8*)(As + row * 64 + g * 8);
            }
#pragma unroll
            for (int nt = 0; nt < 4; ++nt) {
                const int row = (wn << 6) + (nt << 4) + r;
                const int g = ((ks << 2) + q) ^ (row & 7);
                fb[nt] = *(const short8*)(Bs + row * 64 + g * 8);
            }
#pragma unroll
            for (int mt = 0; mt < 4; ++mt)
#pragma unroll
                for (int nt = 0; nt < 4; ++nt)
                    acc[mt][nt] = __builtin_amdgcn_mfma_f32_16x16x32_bf16(
                        fa[mt], fb[nt], acc[mt][nt], 0, 0, 0);
        }
    }

    // epilogue: lane holds rows (wm*64 + mt*16 + q*4 + reg), col (wn*64 + nt*16 + r)
    float ev[4];
#pragma unroll
    for (int nt = 0; nt < 4; ++nt) ev[nt] = e_sq[n0 + (wn << 6) + (nt << 4) + r];
#pragma unroll
    for (int mt = 0; mt < 4; ++mt) {
#pragma unroll
        for (int reg = 0; reg < 4; ++reg) {
            float mv = 1e30f; int mk = 0;
#pragma unroll
            for (int nt = 0; nt < 4; ++nt) {
                float v = 1.0f + ev[nt] - 2.0f * acc[mt][nt][reg];
                if (v < mv) { mv = v; mk = n0 + (wn << 6) + (nt << 4) + r; }
            }
            u64 pk = ((u64)__float_as_uint(mv) << 32) | (unsigned)mk;
#pragma unroll
            for (int off = 1; off < 16; off <<= 1) {
                u64 o = __shfl_xor(pk, off, 64);
                if (o < pk) pk = o;
            }
            if (r == 0) {
                int pos = m0 + (wm << 6) + (mt << 4) + (q << 2) + reg;
                atomicMin(&packed[pos], pk);
            }
        }
    }
}

// ------------------------------------------------ z_q gather
__global__ void gather_kernel(const float* __restrict__ emb,
                              const u64* __restrict__ packed, float* __restrict__ out)
{
    unsigned i = blockIdx.x * 256 + threadIdx.x;
    int w = i & 31, h = (i >> 5) & 31, c = (i >> 10) & 255, b = i >> 18;
    int pos = (b << 10) | (h << 5) | w;
    unsigned idx = (unsigned)(packed[pos] & 0xFFFFFFFFull);
    out[i] = emb[(size_t)idx * CDIM + c];
}

// ------------------------------------------------ loss
__global__ void loss_kernel(const u64* __restrict__ packed,
                            const float* __restrict__ z_sq, float* __restrict__ loss)
{
    int i = blockIdx.x * 256 + threadIdx.x;
    float d = z_sq[i] + (__uint_as_float((unsigned)(packed[i] >> 32)) - 1.0f);
#pragma unroll
    for (int off = 32; off >= 1; off >>= 1) d += __shfl_down(d, off, 64);
    __shared__ float red[4];
    int lane = threadIdx.x & 63, wv = threadIdx.x >> 6;
    if (lane == 0) red[wv] = d;
    __syncthreads();
    if (threadIdx.x == 0) {
        float s = (red[0] + red[1]) + (red[2] + red[3]);
        atomicAdd(loss, s * (1.25f / 16777216.f));
    }
}

extern "C" void kernel_launch(void* const* d_in, const int* in_sizes, int n_in,
                              void* d_out, int out_size, void* d_ws, size_t ws_size,
                              hipStream_t stream)
{
    const float* z   = (const float*)d_in[0];
    const float* emb = (const float*)d_in[1];
    float* out = (float*)d_out;

    ushort* zt    = (ushort*)d_ws;                                  // 64 MB
    ushort* emb2  = (ushort*)((char*)d_ws + 67108864);              // 1 MB
    u64*    packed= (u64*)  ((char*)d_ws + 68157440);               // 512 KB
    float*  z_sq  = (float*)((char*)d_ws + 68681728);               // 256 KB
    float*  e_sq  = (float*)((char*)d_ws + 68943872);               // 4 KB
    float*  loss  = out + 16777216;

    hipMemsetAsync(packed, 0xFF, (size_t)NPOS * 8, stream);
    hipMemsetAsync(z_sq, 0, (size_t)NPOS * 4, stream);
    hipMemsetAsync(loss, 0, sizeof(float), stream);

    emb_prep<<<KCODES, 64, 0, stream>>>(emb, emb2, e_sq);
    zprep<<<dim3(1024, 4), 256, 0, stream>>>(z, zt, z_sq);
    mfma_gemm_argmin<<<dim3(512, 8), 256, 0, stream>>>(zt, emb2, e_sq, packed);
    gather_kernel<<<65536, 256, 0, stream>>>(emb, packed, out);
    loss_kernel<<<256, 256, 0, stream>>>(packed, z_sq, loss);
}

// Round 3
// 280.198 us; speedup vs baseline: 2.3769x; 1.2436x over previous
//
#include <hip/hip_runtime.h>
#include <stdint.h>

typedef unsigned long long u64;
typedef __attribute__((ext_vector_type(8))) short short8;
typedef __attribute__((ext_vector_type(4))) float floatx4;

#define NPOS   65536
#define CDIM   256
#define KCODES 1024

__device__ __forceinline__ ushort f2bf(float x) {
    unsigned u = __float_as_uint(x);
    return (ushort)((u + 0x7FFFu + ((u >> 16) & 1u)) >> 16);
}
__device__ __forceinline__ void gload16(const void* g, void* l) {
    __builtin_amdgcn_global_load_lds((const __attribute__((address_space(1))) void*)g,
                                     (__attribute__((address_space(3))) void*)l, 16, 0, 0);
}

// ------------------------------------------------ emb -> [k][256] bf16 hi + e_sq
__global__ void emb_prep(const float* __restrict__ emb, ushort* __restrict__ emb2,
                         float* __restrict__ e_sq) {
    int k = blockIdx.x, l = threadIdx.x;            // 64 lanes
    float4 v = ((const float4*)(emb + (size_t)k * CDIM))[l];
    float s = v.x * v.x + v.y * v.y + v.z * v.z + v.w * v.w;
    *(ushort4*)(emb2 + (size_t)k * 256 + l * 4) =
        make_ushort4(f2bf(v.x), f2bf(v.y), f2bf(v.z), f2bf(v.w));
#pragma unroll
    for (int off = 32; off >= 1; off >>= 1) s += __shfl_down(s, off, 64);
    if (l == 0) e_sq[k] = s;
}

// ------------------------------------------------ z [64][256][1024] -> zt [pos][256] bf16 hi, + z_sq
__global__ __launch_bounds__(256)
void zprep(const float* __restrict__ z, ushort* __restrict__ zt, float* __restrict__ z_sq)
{
    __shared__ float tile[64][65];
    __shared__ float red[4][64];
    const int t = threadIdx.x;
    const int b = blockIdx.x >> 4, st = blockIdx.x & 15, ct = blockIdx.y;
    const int s0 = st << 6, c0 = ct << 6;
    const int s_in = t & 63, c_grp = t >> 6;
    const float* zp = z + ((size_t)b * 256 + c0 + c_grp * 16) * 1024 + s0 + s_in;
    float ps = 0.f;
#pragma unroll
    for (int i = 0; i < 16; ++i) {
        float v = zp[(size_t)i * 1024];
        tile[c_grp * 16 + i][s_in] = v;
        ps = fmaf(v, v, ps);
    }
    red[c_grp][s_in] = ps;
    __syncthreads();
    if (t < 64) {
        float s = (red[0][t] + red[1][t]) + (red[2][t] + red[3][t]);
        atomicAdd(&z_sq[b * 1024 + s0 + t], s);
    }
    const int cp = t & 31, pg = t >> 5;
#pragma unroll
    for (int j = 0; j < 8; ++j) {
        int p = (pg << 3) + j;
        float v0 = tile[2 * cp + 0][p], v1 = tile[2 * cp + 1][p];
        size_t rowb = (size_t)(b * 1024 + s0 + p) * 256 + c0 + 2 * cp;
        *(ushort2*)(zt + rowb) = make_ushort2(f2bf(v0), f2bf(v1));
    }
}

// ------------------------------------------------ MFMA GEMM (K=256 bf16) + argmin
// tile 128 pos x 256 codes, 4 waves (2x2), wave tile 64 x 128
__global__ __launch_bounds__(256)
void mfma_gemm_argmin(const ushort* __restrict__ zt, const ushort* __restrict__ emb2,
                      const float* __restrict__ e_sq, u64* __restrict__ packed)
{
    __shared__ ushort As[128 * 64];   // 16 KB, XOR-swizzled granules of 8 bf16
    __shared__ ushort Bs[256 * 64];   // 32 KB

    const int tid  = threadIdx.x;
    const int wave = tid >> 6, lane = tid & 63;
    // XCD-aware remap: 4 n-chunks of one m-tile adjacent on the same XCD
    const int l = blockIdx.x;                 // 2048 blocks
    const int xcd = l & 7, slot = l >> 3;
    const int n0 = (slot & 3) << 8;           // code chunk base (0..768)
    const int m0 = (((slot >> 2) << 3) + xcd) << 7;   // position base
    const int wm = wave & 1, wn = wave >> 1;  // wave tile: m 64, n 128
    const int srow = lane >> 3, scol = lane & 7;
    const int q = lane >> 4, r = lane & 15;

    floatx4 acc[4][8] = {};

    for (int kt = 0; kt < 4; ++kt) {
        const int kb = kt << 6;
        __syncthreads();
#pragma unroll
        for (int i = 0; i < 4; ++i) {
            const int row = (i << 5) + (wave << 3) + srow;
            const int src16 = scol ^ (row & 7);
            gload16(zt + (size_t)(m0 + row) * 256 + kb + src16 * 8, As + row * 64 + scol * 8);
        }
#pragma unroll
        for (int i = 0; i < 8; ++i) {
            const int row = (i << 5) + (wave << 3) + srow;
            const int src16 = scol ^ (row & 7);
            gload16(emb2 + (size_t)(n0 + row) * 256 + kb + src16 * 8, Bs + row * 64 + scol * 8);
        }
        __syncthreads();
#pragma unroll
        for (int ks = 0; ks < 2; ++ks) {
            short8 fa[4], fb[8];
#pragma unroll
            for (int mt = 0; mt < 4; ++mt) {
                const int row = (wm << 6) + (mt << 4) + r;
                const int g = ((ks << 2) + q) ^ (row & 7);
                fa[mt] = *(const short8*)(As + row * 64 + g * 8);
            }
#pragma unroll
            for (int nt = 0; nt < 8; ++nt) {
                const int row = (wn << 7) + (nt << 4) + r;
                const int g = ((ks << 2) + q) ^ (row & 7);
                fb[nt] = *(const short8*)(Bs + row * 64 + g * 8);
            }
#pragma unroll
            for (int mt = 0; mt < 4; ++mt)
#pragma unroll
                for (int nt = 0; nt < 8; ++nt)
                    acc[mt][nt] = __builtin_amdgcn_mfma_f32_16x16x32_bf16(
                        fa[mt], fb[nt], acc[mt][nt], 0, 0, 0);
        }
    }

    // epilogue: lane holds rows (wm*64 + mt*16 + q*4 + reg), col (wn*128 + nt*16 + r)
    float ev[8];
#pragma unroll
    for (int nt = 0; nt < 8; ++nt) ev[nt] = e_sq[n0 + (wn << 7) + (nt << 4) + r];
#pragma unroll
    for (int mt = 0; mt < 4; ++mt) {
#pragma unroll
        for (int reg = 0; reg < 4; ++reg) {
            float mv = 1e30f; int mk = 0;
#pragma unroll
            for (int nt = 0; nt < 8; ++nt) {
                float v = 1.0f + ev[nt] - 2.0f * acc[mt][nt][reg];
                if (v < mv) { mv = v; mk = n0 + (wn << 7) + (nt << 4) + r; }
            }
            u64 pk = ((u64)__float_as_uint(mv) << 32) | (unsigned)mk;
#pragma unroll
            for (int off = 1; off < 16; off <<= 1) {
                u64 o = __shfl_xor(pk, off, 64);
                if (o < pk) pk = o;
            }
            if (r == 0) {
                int pos = m0 + (wm << 6) + (mt << 4) + (q << 2) + reg;
                atomicMin(&packed[pos], pk);
            }
        }
    }
}

// ------------------------------------------------ z_q gather
__global__ void gather_kernel(const float* __restrict__ emb,
                              const u64* __restrict__ packed, float* __restrict__ out)
{
    unsigned i = blockIdx.x * 256 + threadIdx.x;
    int w = i & 31, h = (i >> 5) & 31, c = (i >> 10) & 255, b = i >> 18;
    int pos = (b << 10) | (h << 5) | w;
    unsigned idx = (unsigned)(packed[pos] & 0xFFFFFFFFull);
    out[i] = emb[(size_t)idx * CDIM + c];
}

// ------------------------------------------------ loss
__global__ void loss_kernel(const u64* __restrict__ packed,
                            const float* __restrict__ z_sq, float* __restrict__ loss)
{
    int i = blockIdx.x * 256 + threadIdx.x;
    float d = z_sq[i] + (__uint_as_float((unsigned)(packed[i] >> 32)) - 1.0f);
#pragma unroll
    for (int off = 32; off >= 1; off >>= 1) d += __shfl_down(d, off, 64);
    __shared__ float red[4];
    int lane = threadIdx.x & 63, wv = threadIdx.x >> 6;
    if (lane == 0) red[wv] = d;
    __syncthreads();
    if (threadIdx.x == 0) {
        float s = (red[0] + red[1]) + (red[2] + red[3]);
        atomicAdd(loss, s * (1.25f / 16777216.f));
    }
}

extern "C" void kernel_launch(void* const* d_in, const int* in_sizes, int n_in,
                              void* d_out, int out_size, void* d_ws, size_t ws_size,
                              hipStream_t stream)
{
    const float* z   = (const float*)d_in[0];
    const float* emb = (const float*)d_in[1];
    float* out = (float*)d_out;

    ushort* zt     = (ushort*)d_ws;                                  // 32 MB
    ushort* emb2   = (ushort*)((char*)d_ws + 33554432);              // 512 KB
    u64*    packed = (u64*)  ((char*)d_ws + 34078720);               // 512 KB
    float*  z_sq   = (float*)((char*)d_ws + 34603008);               // 256 KB
    float*  e_sq   = (float*)((char*)d_ws + 34865152);               // 4 KB
    float*  loss   = out + 16777216;

    hipMemsetAsync(packed, 0xFF, (size_t)NPOS * 8, stream);
    hipMemsetAsync(z_sq, 0, (size_t)NPOS * 4, stream);
    hipMemsetAsync(loss, 0, sizeof(float), stream);

    emb_prep<<<KCODES, 64, 0, stream>>>(emb, emb2, e_sq);
    zprep<<<dim3(1024, 4), 256, 0, stream>>>(z, zt, z_sq);
    mfma_gemm_argmin<<<2048, 256, 0, stream>>>(zt, emb2, e_sq, packed);
    gather_kernel<<<65536, 256, 0, stream>>>(emb, packed, out);
    loss_kernel<<<256, 256, 0, stream>>>(packed, z_sq, loss);
}

// Round 4
// 221.664 us; speedup vs baseline: 3.0045x; 1.2641x over previous
//
#include <hip/hip_runtime.h>
#include <stdint.h>

typedef unsigned long long u64;
typedef __attribute__((ext_vector_type(8))) short short8;
typedef __attribute__((ext_vector_type(4))) float floatx4;

#define NPOS   65536
#define CDIM   256
#define KCODES 1024

__device__ __forceinline__ ushort f2bf(float x) {
    unsigned u = __float_as_uint(x);
    return (ushort)((u + 0x7FFFu + ((u >> 16) & 1u)) >> 16);
}
__device__ __forceinline__ void gload16(const void* g, void* l) {
    __builtin_amdgcn_global_load_lds((const __attribute__((address_space(1))) void*)g,
                                     (__attribute__((address_space(3))) void*)l, 16, 0, 0);
}
__device__ __forceinline__ u64 umin64(u64 a, u64 b) { return a < b ? a : b; }

// ------------------------------------------------ emb -> [k][256] bf16 + e_sq
__global__ void emb_prep(const float* __restrict__ emb, ushort* __restrict__ emb2,
                         float* __restrict__ e_sq) {
    int k = blockIdx.x, l = threadIdx.x;            // 64 lanes
    float4 v = ((const float4*)(emb + (size_t)k * CDIM))[l];
    float s = v.x * v.x + v.y * v.y + v.z * v.z + v.w * v.w;
    *(ushort4*)(emb2 + (size_t)k * 256 + l * 4) =
        make_ushort4(f2bf(v.x), f2bf(v.y), f2bf(v.z), f2bf(v.w));
#pragma unroll
    for (int off = 32; off >= 1; off >>= 1) s += __shfl_down(s, off, 64);
    if (l == 0) e_sq[k] = s;
}

// ------------------------------------------------ z -> zt [pos][256] bf16, + z_sq (no atomics)
// one block: 64 positions x 256 channels
__global__ __launch_bounds__(256)
void zprep(const float* __restrict__ z, ushort* __restrict__ zt, float* __restrict__ z_sq)
{
    __shared__ float tile[256][65];    // [c][s], pad 65 -> 2-way max (free)
    __shared__ float red[4][64];
    const int t = threadIdx.x;
    const int b = blockIdx.x >> 4, st = blockIdx.x & 15;
    const int s0 = st << 6;
    const int s_in = t & 63, cg = t >> 6;            // cg = wave id (uniform per wave)
    const float* zp = z + ((size_t)b * 256 + cg) * 1024 + s0 + s_in;
    float ps = 0.f;
#pragma unroll
    for (int i = 0; i < 64; ++i) {                   // c = cg + 4*i
        float v = zp[(size_t)i * 4096];
        tile[cg + 4 * i][s_in] = v;
        ps = fmaf(v, v, ps);
    }
    red[cg][s_in] = ps;
    __syncthreads();
    if (t < 64)
        z_sq[b * 1024 + s0 + t] = (red[0][t] + red[1][t]) + (red[2][t] + red[3][t]);
    const int pair = t & 127, pg = t >> 7;           // 128 c-pairs x 2 pos-groups
#pragma unroll
    for (int j = 0; j < 32; ++j) {
        int p = (pg << 5) + j;
        float v0 = tile[2 * pair][p], v1 = tile[2 * pair + 1][p];
        *(ushort2*)(zt + (size_t)(b * 1024 + s0 + p) * 256 + 2 * pair) =
            make_ushort2(f2bf(v0), f2bf(v1));
    }
}

// ------------------------------------------------ MFMA GEMM (K=256 bf16) + argmin
// 512 threads, block tile 128 pos x 256 codes, 8 waves (2m x 4n), wave tile 64x64
__global__ __launch_bounds__(512)
void mfma_gemm_argmin(const ushort* __restrict__ zt, const ushort* __restrict__ emb2,
                      const float* __restrict__ e_sq, u64* __restrict__ packed)
{
    __shared__ ushort As[128 * 64];    // 16 KB, XOR-swizzled 8-bf16 granules
    __shared__ ushort Bs[256 * 64];    // 32 KB
    __shared__ u64 red[128][4];        // 4 KB argmin pre-reduce

    const int tid  = threadIdx.x;
    const int wave = tid >> 6, lane = tid & 63;
    // XCD-aware: 4 n-chunks of one m-tile adjacent on one XCD
    const int l = blockIdx.x;                  // 2048 blocks
    const int xcd = l & 7, slot = l >> 3;
    const int n0 = (slot & 3) << 8;            // 0..768
    const int m0 = (((slot >> 2) << 3) + xcd) << 7;
    const int wm = wave & 1, wn = wave >> 1;   // 2 x 4 wave grid
    const int srow = tid >> 3, scol = tid & 7; // staging: 64 rows x 8 granules per pass
    const int q = lane >> 4, r = lane & 15;

    floatx4 acc[4][4] = {};

    for (int kt = 0; kt < 4; ++kt) {
        const int kb = kt << 6;
        __syncthreads();
#pragma unroll
        for (int i = 0; i < 2; ++i) {          // A: 128 rows
            const int row = (i << 6) + srow;
            const int src16 = scol ^ (row & 7);
            gload16(zt + (size_t)(m0 + row) * 256 + kb + src16 * 8, As + row * 64 + scol * 8);
        }
#pragma unroll
        for (int i = 0; i < 4; ++i) {          // B: 256 rows
            const int row = (i << 6) + srow;
            const int src16 = scol ^ (row & 7);
            gload16(emb2 + (size_t)(n0 + row) * 256 + kb + src16 * 8, Bs + row * 64 + scol * 8);
        }
        __syncthreads();
#pragma unroll
        for (int ks = 0; ks < 2; ++ks) {
            short8 fa[4], fb[4];
#pragma unroll
            for (int mt = 0; mt < 4; ++mt) {
                const int row = (wm << 6) + (mt << 4) + r;
                const int g = ((ks << 2) + q) ^ (row & 7);
                fa[mt] = *(const short8*)(As + row * 64 + g * 8);
            }
#pragma unroll
            for (int nt = 0; nt < 4; ++nt) {
                const int row = (wn << 6) + (nt << 4) + r;
                const int g = ((ks << 2) + q) ^ (row & 7);
                fb[nt] = *(const short8*)(Bs + row * 64 + g * 8);
            }
#pragma unroll
            for (int mt = 0; mt < 4; ++mt)
#pragma unroll
                for (int nt = 0; nt < 4; ++nt)
                    acc[mt][nt] = __builtin_amdgcn_mfma_f32_16x16x32_bf16(
                        fa[mt], fb[nt], acc[mt][nt], 0, 0, 0);
        }
    }

    // epilogue: lane row = wm*64+mt*16+q*4+reg, col = wn*64+nt*16+r
    float ev[4];
#pragma unroll
    for (int nt = 0; nt < 4; ++nt) ev[nt] = e_sq[n0 + (wn << 6) + (nt << 4) + r];
#pragma unroll
    for (int mt = 0; mt < 4; ++mt) {
#pragma unroll
        for (int reg = 0; reg < 4; ++reg) {
            float mv = 1e30f; int mk = 0;
#pragma unroll
            for (int nt = 0; nt < 4; ++nt) {
                float v = 1.0f + ev[nt] - 2.0f * acc[mt][nt][reg];
                if (v < mv) { mv = v; mk = n0 + (wn << 6) + (nt << 4) + r; }
            }
            u64 pk = ((u64)__float_as_uint(mv) << 32) | (unsigned)mk;
#pragma unroll
            for (int off = 1; off < 16; off <<= 1) {
                u64 o = __shfl_xor(pk, off, 64);
                if (o < pk) pk = o;
            }
            if (r == 0)
                red[(wm << 6) + (mt << 4) + (q << 2) + reg][wn] = pk;
        }
    }
    __syncthreads();
    if (tid < 128) {
        u64 m = umin64(umin64(red[tid][0], red[tid][1]), umin64(red[tid][2], red[tid][3]));
        atomicMin(&packed[m0 + tid], m);
    }
}

// ------------------------------------------------ gather (coalesced via LDS) + loss
// one block per (b,h): 32 positions, stage 32 emb rows, write out coalesced in w
__global__ __launch_bounds__(256)
void gather_loss(const float* __restrict__ emb, const u64* __restrict__ packed,
                 const float* __restrict__ z_sq, float* __restrict__ out,
                 float* __restrict__ loss)
{
    __shared__ float sm[32][260];      // padded, 16B-aligned rows
    __shared__ unsigned sidx[32];
    const int t = threadIdx.x;
    const int bh = blockIdx.x;         // 2048 = b*32 + h
    const int b = bh >> 5, h = bh & 31;
    const int pos0 = bh << 5;

    float d = 0.f;
    if (t < 32) {
        u64 pk = packed[pos0 + t];
        sidx[t] = (unsigned)pk;
        d = z_sq[pos0 + t] + __uint_as_float((unsigned)(pk >> 32)) - 1.0f;
    }
    if (t < 64) {
#pragma unroll
        for (int off = 16; off >= 1; off >>= 1) d += __shfl_down(d, off, 64);
        if (t == 0) atomicAdd(loss, d * (1.25f / 16777216.f));
    }
    __syncthreads();
    // stage 32 emb rows (coalesced float4 reads)
    {
        const int w = t >> 3, f8 = t & 7;
        const float4* er = (const float4*)(emb + (size_t)sidx[w] * CDIM);
#pragma unroll
        for (int j = 0; j < 8; ++j) {
            float4 v = er[f8 + j * 8];
            *(float4*)&sm[w][(f8 + j * 8) * 4] = v;
        }
    }
    __syncthreads();
    // write out: coalesced along w
    const int w2 = t & 31, cg = t >> 5;          // 8 c-groups of 32
    float* ob = out + (size_t)b * 262144 + (size_t)cg * 32768 + h * 32 + w2;
#pragma unroll
    for (int cc = 0; cc < 32; ++cc)
        ob[(size_t)cc * 1024] = sm[w2][(cg << 5) + cc];
}

extern "C" void kernel_launch(void* const* d_in, const int* in_sizes, int n_in,
                              void* d_out, int out_size, void* d_ws, size_t ws_size,
                              hipStream_t stream)
{
    const float* z   = (const float*)d_in[0];
    const float* emb = (const float*)d_in[1];
    float* out = (float*)d_out;

    ushort* zt     = (ushort*)d_ws;                                  // 32 MB
    ushort* emb2   = (ushort*)((char*)d_ws + 33554432);              // 512 KB
    u64*    packed = (u64*)  ((char*)d_ws + 34078720);               // 512 KB
    float*  z_sq   = (float*)((char*)d_ws + 34603008);               // 256 KB
    float*  e_sq   = (float*)((char*)d_ws + 34865152);               // 4 KB
    float*  loss   = out + 16777216;

    hipMemsetAsync(packed, 0xFF, (size_t)NPOS * 8, stream);
    hipMemsetAsync(loss, 0, sizeof(float), stream);

    emb_prep<<<KCODES, 64, 0, stream>>>(emb, emb2, e_sq);
    zprep<<<1024, 256, 0, stream>>>(z, zt, z_sq);
    mfma_gemm_argmin<<<2048, 512, 0, stream>>>(zt, emb2, e_sq, packed);
    gather_loss<<<2048, 256, 0, stream>>>(emb, packed, z_sq, out, loss);
}

// Round 5
// 168.116 us; speedup vs baseline: 3.9615x; 1.3185x over previous
//
#include <hip/hip_runtime.h>
#include <stdint.h>

typedef unsigned long long u64;
typedef __attribute__((ext_vector_type(8))) short short8;
typedef __attribute__((ext_vector_type(4))) float floatx4;

#define NPOS   65536
#define CDIM   256
#define KCODES 1024

__device__ __forceinline__ ushort f2bf(float x) {
    unsigned u = __float_as_uint(x);
    return (ushort)((u + 0x7FFFu + ((u >> 16) & 1u)) >> 16);
}
__device__ __forceinline__ void gload16(const void* g, void* l) {
    __builtin_amdgcn_global_load_lds((const __attribute__((address_space(1))) void*)g,
                                     (__attribute__((address_space(3))) void*)l, 16, 0, 0);
}
__device__ __forceinline__ u64 umin64(u64 a, u64 b) { return a < b ? a : b; }

// ------------------------------------------------ emb -> [k][256] bf16 + e_sq
__global__ void emb_prep(const float* __restrict__ emb, ushort* __restrict__ emb2,
                         float* __restrict__ e_sq) {
    int k = blockIdx.x, l = threadIdx.x;            // 64 lanes
    float4 v = ((const float4*)(emb + (size_t)k * CDIM))[l];
    float s = v.x * v.x + v.y * v.y + v.z * v.z + v.w * v.w;
    *(ushort4*)(emb2 + (size_t)k * 256 + l * 4) =
        make_ushort4(f2bf(v.x), f2bf(v.y), f2bf(v.z), f2bf(v.w));
#pragma unroll
    for (int off = 32; off >= 1; off >>= 1) s += __shfl_down(s, off, 64);
    if (l == 0) e_sq[k] = s;
}

// ------------------------------------------------ fused: transpose + GEMM-argmin + gather + loss
// one block = 64 positions; K=256; all 1024 codes streamed through LDS
__global__ __launch_bounds__(256, 2)
void vq_fused(const float* __restrict__ z, const float* __restrict__ emb,
              const ushort* __restrict__ emb2, const float* __restrict__ e_sq,
              float* __restrict__ out, float* __restrict__ loss)
{
    __shared__ __align__(16) char smem[70144];
    ushort* As  = (ushort*)smem;                  // [64 pos][256 k] bf16, XOR-swizzled (32 KB)
    ushort* Bs  = (ushort*)(smem + 32768);        // [256 code][64 k] bf16, XOR-swizzled (32 KB)
    float*  smG = (float*)smem;                   // [64][260] fp32 gather (re-uses As+Bs)
    u64*    red = (u64*)(smem + 66560);           // [64 pos][4 wave]
    float*  z2p = (float*)(smem + 68608);         // [4][64]
    float*  z2  = (float*)(smem + 69632);         // [64]
    unsigned* sidx = (unsigned*)(smem + 69888);   // [64]

    const int tid  = threadIdx.x;
    const int wave = tid >> 6, lane = tid & 63;
    const int q = lane >> 4, r = lane & 15;
    const int m0 = blockIdx.x << 6;               // 1024 blocks x 64 positions
    const int b = m0 >> 10, s0 = m0 & 1023;

    // ---- phase 0: load z tile fp32, z_sq partials, transpose->bf16 LDS ----
    {
        const int p = tid & 63, cg = tid >> 6;    // p: position (coalesced), cg: c-quarter
        const float* zp = z + ((size_t)(b * 256 + cg * 64)) * 1024 + s0 + p;
        float ps = 0.f;
#pragma unroll 4
        for (int i4 = 0; i4 < 16; ++i4) {
            float v0 = zp[(size_t)(i4 * 4 + 0) * 1024];
            float v1 = zp[(size_t)(i4 * 4 + 1) * 1024];
            float v2 = zp[(size_t)(i4 * 4 + 2) * 1024];
            float v3 = zp[(size_t)(i4 * 4 + 3) * 1024];
            ps = fmaf(v0, v0, fmaf(v1, v1, fmaf(v2, v2, fmaf(v3, v3, ps))));
            const int glin = cg * 8 + (i4 >> 1);
            const int gsw = (glin & ~7) | ((glin & 7) ^ (p & 7));
            *(ushort4*)(As + p * 256 + gsw * 8 + (i4 & 1) * 4) =
                make_ushort4(f2bf(v0), f2bf(v1), f2bf(v2), f2bf(v3));
        }
        z2p[cg * 64 + p] = ps;
    }
    __syncthreads();
    if (tid < 64)
        z2[tid] = (z2p[tid] + z2p[64 + tid]) + (z2p[128 + tid] + z2p[192 + tid]);

    // ---- main loop: 4 n-chunks of 256 codes, K=256 in 4 chunks of 64 ----
    floatx4 acc[4][4] = {};
    u64 run[16];
#pragma unroll
    for (int j = 0; j < 16; ++j) run[j] = ~0ull;

    for (int nc = 0; nc < 4; ++nc) {
        const int n0 = nc << 8;
        for (int kt = 0; kt < 4; ++kt) {
            __syncthreads();
#pragma unroll
            for (int i = 0; i < 8; ++i) {          // stage B: 256 rows x 64 k
                const int row = (i << 5) + (tid >> 3);
                const int scol = tid & 7;
                const int src = scol ^ (row & 7);
                gload16(emb2 + (size_t)(n0 + row) * 256 + (kt << 6) + src * 8,
                        Bs + row * 64 + scol * 8);
            }
            __syncthreads();
#pragma unroll
            for (int ks = 0; ks < 2; ++ks) {
                short8 fa[4], fb[4];
#pragma unroll
                for (int mt = 0; mt < 4; ++mt) {
                    const int row = (mt << 4) + r;
                    const int gl = (kt << 3) + (ks << 2) + q;
                    const int gs = (gl & ~7) | ((gl & 7) ^ (row & 7));
                    fa[mt] = *(const short8*)(As + row * 256 + gs * 8);
                }
#pragma unroll
                for (int nt = 0; nt < 4; ++nt) {
                    const int row = (wave << 6) + (nt << 4) + r;
                    const int gs = ((ks << 2) + q) ^ (row & 7);
                    fb[nt] = *(const short8*)(Bs + row * 64 + gs * 8);
                }
#pragma unroll
                for (int mt = 0; mt < 4; ++mt)
#pragma unroll
                    for (int nt = 0; nt < 4; ++nt)
                        acc[mt][nt] = __builtin_amdgcn_mfma_f32_16x16x32_bf16(
                            fa[mt], fb[nt], acc[mt][nt], 0, 0, 0);
            }
        }
        // fold this n-chunk into running argmin; val = 4 + e_sq - 2 z.e > 0
        float ev[4];
#pragma unroll
        for (int nt = 0; nt < 4; ++nt) ev[nt] = e_sq[n0 + (wave << 6) + (nt << 4) + r];
#pragma unroll
        for (int mt = 0; mt < 4; ++mt) {
#pragma unroll
            for (int reg = 0; reg < 4; ++reg) {
                float mv = 1e30f; int mk = 0;
#pragma unroll
                for (int nt = 0; nt < 4; ++nt) {
                    float v = 4.0f + ev[nt] - 2.0f * acc[mt][nt][reg];
                    if (v < mv) { mv = v; mk = n0 + (wave << 6) + (nt << 4) + r; }
                }
                u64 pk = ((u64)__float_as_uint(mv) << 32) | (unsigned)mk;
                run[(mt << 2) + reg] = umin64(run[(mt << 2) + reg], pk);
            }
#pragma unroll
            for (int nt = 0; nt < 4; ++nt) acc[mt][nt] = (floatx4){0.f, 0.f, 0.f, 0.f};
        }
    }

    // ---- cross-lane/wave argmin merge ----
#pragma unroll
    for (int j = 0; j < 16; ++j) {
        u64 pk = run[j];
#pragma unroll
        for (int off = 1; off < 16; off <<= 1)
            pk = umin64(pk, __shfl_xor(pk, off, 64));
        if (r == 0) {
            const int pos = ((j >> 2) << 4) + (q << 2) + (j & 3);  // mt*16 + q*4 + reg
            red[pos * 4 + wave] = pk;
        }
    }
    __syncthreads();
    if (tid < 64) {
        u64 m = umin64(umin64(red[tid * 4 + 0], red[tid * 4 + 1]),
                       umin64(red[tid * 4 + 2], red[tid * 4 + 3]));
        sidx[tid] = (unsigned)m;
        float d = z2[tid] + __uint_as_float((unsigned)(m >> 32)) - 4.0f;
#pragma unroll
        for (int off = 32; off >= 1; off >>= 1) d += __shfl_down(d, off, 64);
        if (tid == 0) atomicAdd(loss, d * (1.25f / 16777216.f));
    }
    __syncthreads();

    // ---- gather: stage 64 chosen emb rows fp32 into smG (As/Bs dead) ----
#pragma unroll
    for (int i = 0; i < 16; ++i) {
        const int row = (wave << 4) + i;
        const float* src = emb + (size_t)sidx[row] * CDIM;   // lane-uniform value
        gload16(src + lane * 4, smG + row * 260 + lane * 4);
    }
    __syncthreads();

    // ---- write z_q coalesced along s ----
    {
        const int s = tid & 63, cgq = tid >> 6;
        float* ob = out + ((size_t)(b * 256 + cgq * 64)) * 1024 + s0 + s;
#pragma unroll
        for (int c4 = 0; c4 < 16; ++c4) {
            float4 v = *(const float4*)(smG + s * 260 + cgq * 64 + c4 * 4);
            ob[(size_t)(c4 * 4 + 0) * 1024] = v.x;
            ob[(size_t)(c4 * 4 + 1) * 1024] = v.y;
            ob[(size_t)(c4 * 4 + 2) * 1024] = v.z;
            ob[(size_t)(c4 * 4 + 3) * 1024] = v.w;
        }
    }
}

extern "C" void kernel_launch(void* const* d_in, const int* in_sizes, int n_in,
                              void* d_out, int out_size, void* d_ws, size_t ws_size,
                              hipStream_t stream)
{
    const float* z   = (const float*)d_in[0];
    const float* emb = (const float*)d_in[1];
    float* out = (float*)d_out;

    ushort* emb2 = (ushort*)d_ws;                         // 512 KB
    float*  e_sq = (float*)((char*)d_ws + 524288);        // 4 KB
    float*  loss = out + 16777216;

    hipMemsetAsync(loss, 0, sizeof(float), stream);
    emb_prep<<<KCODES, 64, 0, stream>>>(emb, emb2, e_sq);
    vq_fused<<<1024, 256, 0, stream>>>(z, emb, emb2, e_sq, out, loss);
}

// Round 6
// 158.102 us; speedup vs baseline: 4.2124x; 1.0633x over previous
//
#include <hip/hip_runtime.h>
#include <stdint.h>

typedef unsigned long long u64;
typedef __attribute__((ext_vector_type(4))) float floatx4;
typedef __attribute__((ext_vector_type(2))) long longx2;

#define NPOS   65536
#define CDIM   256
#define KCODES 1024

__device__ __forceinline__ void gload16(const void* g, void* l) {
    __builtin_amdgcn_global_load_lds((const __attribute__((address_space(1))) void*)g,
                                     (__attribute__((address_space(3))) void*)l, 16, 0, 0);
}
__device__ __forceinline__ unsigned pk4_fp8(float a, float b, float c, float d) {
    int u = __builtin_amdgcn_cvt_pk_fp8_f32(a, b, 0, false);
    u = __builtin_amdgcn_cvt_pk_fp8_f32(c, d, u, true);
    return (unsigned)u;
}

// ---------------- emb -> emb8 [k][256B] fp8(256*e), K-permuted; e_sqs = 4096*e_sq
__global__ void emb_prep(const float* __restrict__ emb, unsigned char* __restrict__ emb8,
                         float* __restrict__ e_sqs) {
    int k = blockIdx.x, l = threadIdx.x;            // 64 lanes
    float4 v = ((const float4*)(emb + (size_t)k * CDIM))[l];
    float s = v.x * v.x + v.y * v.y + v.z * v.z + v.w * v.w;
    int c = l * 4;
    int kt = c >> 6, cl = c & 63;
    int ks = cl >> 5, q = (cl & 31) >> 3, j0 = cl & 7;
    unsigned pk = pk4_fp8(v.x * 256.f, v.y * 256.f, v.z * 256.f, v.w * 256.f);
    *(unsigned*)(emb8 + (size_t)k * 256 + kt * 64 + q * 16 + ks * 8 + j0) = pk;
#pragma unroll
    for (int off = 32; off >= 1; off >>= 1) s += __shfl_down(s, off, 64);
    if (l == 0) e_sqs[k] = 4096.f * s;
}

// ---------------- fused: transpose+fp8 convert, fp8 MFMA argmin, gather, loss
__global__ __launch_bounds__(256, 3)
void vq_fused(const float* __restrict__ z, const float* __restrict__ emb,
              const unsigned char* __restrict__ emb8, const float* __restrict__ e_sqs,
              float* __restrict__ out, float* __restrict__ loss)
{
    __shared__ __align__(16) char smem[51712];
    unsigned char* As = (unsigned char*)smem;            // [64 p][256B] K-permuted+swizzled
    unsigned char* Bs = (unsigned char*)(smem + 16384);  // [256 code][128B] (2 kt chunks)
    unsigned* red  = (unsigned*)(smem + 49152);          // [64][4]
    float*  z2p    = (float*)(smem + 50176);             // [4][64]
    float*  z2     = (float*)(smem + 51200);             // [64]
    unsigned* sidx = (unsigned*)(smem + 51456);          // [64]
    float*  smG    = (float*)smem;                       // [32][260] overlay (33,280B)

    const int tid = threadIdx.x, wave = tid >> 6, lane = tid & 63;
    const int q = lane >> 4, r = lane & 15;
    const int m0 = blockIdx.x << 6;
    const int b = m0 >> 10, s0 = m0 & 1023;

    // ---- phase 0: load z, z_sq, convert 16*z -> fp8, K-permute+swizzle into As ----
    {
        const int p = tid & 63, cg = tid >> 6;
        const float* zb = z + ((size_t)(b * 256 + cg * 64)) * 1024 + s0 + p;
        float ps = 0.f;
#pragma unroll
        for (int qq = 0; qq < 4; ++qq)
#pragma unroll
            for (int ks = 0; ks < 2; ++ks) {
                float v[8];
#pragma unroll
                for (int j = 0; j < 8; ++j) {
                    v[j] = zb[(size_t)(ks * 32 + qq * 8 + j) * 1024];
                    ps = fmaf(v[j], v[j], ps);
                }
                uint2 w;
                w.x = pk4_fp8(16.f * v[0], 16.f * v[1], 16.f * v[2], 16.f * v[3]);
                w.y = pk4_fp8(16.f * v[4], 16.f * v[5], 16.f * v[6], 16.f * v[7]);
                const int pgl = cg * 4 + qq;
                const int pgs = (pgl & 8) | ((pgl & 7) ^ (p & 7));
                *(uint2*)(As + p * 256 + pgs * 16 + ks * 8) = w;
            }
        z2p[cg * 64 + p] = ps;
    }
    __syncthreads();
    if (tid < 64)
        z2[tid] = (z2p[tid] + z2p[64 + tid]) + (z2p[128 + tid] + z2p[192 + tid]);

    // ---- K-loop: 4 n-chunks x (2 staging phases of 2 kt) ----
    floatx4 acc[4][4] = {};
    unsigned run[16];
#pragma unroll
    for (int j = 0; j < 16; ++j) run[j] = 0xFFFFFFFFu;

    for (int nc = 0; nc < 4; ++nc) {
        const int n0 = nc << 8;
        for (int ktp = 0; ktp < 2; ++ktp) {
            __syncthreads();
            {   // stage Bs: 256 rows x 128B, swizzle applied on global side
                const int rr = tid >> 3, pg = tid & 7;
#pragma unroll
                for (int i = 0; i < 8; ++i) {
                    const int row = i * 32 + rr;
                    gload16(emb8 + (size_t)(n0 + row) * 256 + ktp * 128 + ((pg ^ (row & 7)) * 16),
                            Bs + row * 128 + pg * 16);
                }
            }
            __syncthreads();
#pragma unroll
            for (int ktl = 0; ktl < 2; ++ktl) {
                const int kt = ktp * 2 + ktl;
                longx2 fa[4], fb[4];
#pragma unroll
                for (int mt = 0; mt < 4; ++mt) {
                    const int p = mt * 16 + r;
                    const int pgl = kt * 4 + q;
                    const int pgs = (pgl & 8) | ((pgl & 7) ^ (r & 7));
                    fa[mt] = *(const longx2*)(As + p * 256 + pgs * 16);
                }
#pragma unroll
                for (int nt = 0; nt < 4; ++nt) {
                    const int row = wave * 64 + nt * 16 + r;
                    const int pgs = (ktl * 4 + q) ^ (r & 7);
                    fb[nt] = *(const longx2*)(Bs + row * 128 + pgs * 16);
                }
#pragma unroll
                for (int mt = 0; mt < 4; ++mt)
#pragma unroll
                    for (int nt = 0; nt < 4; ++nt) {
                        acc[mt][nt] = __builtin_amdgcn_mfma_f32_16x16x32_fp8_fp8(
                            fa[mt][0], fb[nt][0], acc[mt][nt], 0, 0, 0);
                        acc[mt][nt] = __builtin_amdgcn_mfma_f32_16x16x32_fp8_fp8(
                            fa[mt][1], fb[nt][1], acc[mt][nt], 0, 0, 0);
                    }
            }
        }
        // fold: val = 16384 + 4096*e_sq - 2*dot~  (positive); pack u32: (val*32)<<10 | k
        float ev[4];
#pragma unroll
        for (int nt = 0; nt < 4; ++nt) ev[nt] = e_sqs[n0 + wave * 64 + nt * 16 + r];
#pragma unroll
        for (int mt = 0; mt < 4; ++mt) {
#pragma unroll
            for (int reg = 0; reg < 4; ++reg) {
                float mv = 3e7f; int mk = 0;
#pragma unroll
                for (int nt = 0; nt < 4; ++nt) {
                    float v = 16384.f + ev[nt] - 2.f * acc[mt][nt][reg];
                    if (v < mv) { mv = v; mk = n0 + wave * 64 + nt * 16 + r; }
                }
                unsigned pk = ((unsigned)(mv * 32.f) << 10) | (unsigned)mk;
                run[(mt << 2) + reg] = min(run[(mt << 2) + reg], pk);
            }
#pragma unroll
            for (int nt = 0; nt < 4; ++nt) acc[mt][nt] = (floatx4){0.f, 0.f, 0.f, 0.f};
        }
    }

    // ---- argmin merge across lanes/waves ----
#pragma unroll
    for (int j = 0; j < 16; ++j) {
        unsigned pk = run[j];
#pragma unroll
        for (int off = 1; off < 16; off <<= 1)
            pk = min(pk, (unsigned)__shfl_xor((int)pk, off, 64));
        if (r == 0)
            red[(((j >> 2) << 4) + (q << 2) + (j & 3)) * 4 + wave] = pk;
    }
    __syncthreads();
    if (tid < 64) {
        unsigned m = min(min(red[tid * 4 + 0], red[tid * 4 + 1]),
                         min(red[tid * 4 + 2], red[tid * 4 + 3]));
        sidx[tid] = m & 1023u;
        float val = (float)(m >> 10) * (1.f / 32.f);
        float d = z2[tid] + (val - 16384.f) * (1.f / 4096.f);
#pragma unroll
        for (int off = 32; off >= 1; off >>= 1) d += __shfl_down(d, off, 64);
        if (tid == 0) atomicAdd(loss, d * (1.25f / 16777216.f));
    }
    __syncthreads();

    // ---- gather + write z_q: 2 passes of 32 rows through smG overlay ----
    for (int pass = 0; pass < 2; ++pass) {
        const int rbase = pass << 5;
#pragma unroll
        for (int i = 0; i < 8; ++i) {
            const int row = rbase + wave * 8 + i;                     // wave-uniform
            gload16(emb + (size_t)sidx[row] * CDIM + lane * 4,
                    smG + (row - rbase) * 260 + lane * 4);
        }
        __syncthreads();
        {
            const int s = tid & 31, cgq = tid >> 5;                   // 8 groups x 32 c
            float* ob = out + ((size_t)(b * 256 + cgq * 32)) * 1024 + s0 + rbase + s;
#pragma unroll
            for (int c4 = 0; c4 < 8; ++c4) {
                float4 v = *(const float4*)(smG + s * 260 + cgq * 32 + c4 * 4);
                ob[(size_t)(c4 * 4 + 0) * 1024] = v.x;
                ob[(size_t)(c4 * 4 + 1) * 1024] = v.y;
                ob[(size_t)(c4 * 4 + 2) * 1024] = v.z;
                ob[(size_t)(c4 * 4 + 3) * 1024] = v.w;
            }
        }
        __syncthreads();
    }
}

extern "C" void kernel_launch(void* const* d_in, const int* in_sizes, int n_in,
                              void* d_out, int out_size, void* d_ws, size_t ws_size,
                              hipStream_t stream)
{
    const float* z   = (const float*)d_in[0];
    const float* emb = (const float*)d_in[1];
    float* out = (float*)d_out;

    unsigned char* emb8 = (unsigned char*)d_ws;           // 256 KB
    float* e_sqs = (float*)((char*)d_ws + 262144);        // 4 KB
    float* loss  = out + 16777216;

    hipMemsetAsync(loss, 0, sizeof(float), stream);
    emb_prep<<<KCODES, 64, 0, stream>>>(emb, emb8, e_sqs);
    vq_fused<<<1024, 256, 0, stream>>>(z, emb, emb8, e_sqs, out, loss);
}